// Round 1
// baseline (26715.308 us; speedup 1.0000x reference)
//
#include <hip/hip_runtime.h>
#include <stdint.h>

#define NB 64
#define NT 1024
#define ND 512
#define NU 512
#define NC 1024
#define NWG 64
#define GJ 16   // gate cols per WG
#define ZJ 8    // z cols per WG

typedef __attribute__((ext_vector_type(8))) short bf16x8;
typedef __attribute__((ext_vector_type(4))) float f32x4;

__device__ __forceinline__ short f2bf(float f) {
  union { float f; uint32_t u; } v; v.f = f;
  uint32_t r = (v.u + 0x7fffu + ((v.u >> 16) & 1u)) >> 16;
  return (short)(uint16_t)r;
}
__device__ __forceinline__ float bf2f(short s) {
  union { uint32_t u; float f; } v; v.u = ((uint32_t)(uint16_t)s) << 16;
  return v.f;
}
__device__ __forceinline__ float sigm(float x) { return 1.0f / (1.0f + __expf(-x)); }

struct SMem {
  short wgx[GJ * 512];   // Wg[0:512, jcols]^T, bf16, swizzled   (x part)
  short wgz[GJ * 512];   // (gamma*Wg[512:1024, jcols])^T, bf16  (z part)
  short wf[ZJ * 1024];   // Wf[:, jcols]^T, bf16, swizzled
  float gamma_s[NU];
  float beta_s[NU];
  float bfv_s[NU];
  float bg_s[GJ];
  float kb_s[GJ];        // sum_c beta[c]*Wg[512+c][col]
  float kg_s[GJ];        // sum_c gamma[c]*Wg[512+c][col]
  float mu_s[NB];
  float rs_s[NB];
  float red[NB][4][2];
  float red2[GJ][16][2];
};

__device__ __forceinline__ void gbar(uint32_t* root, uint32_t* leaf, unsigned ep) {
  __syncthreads();  // compiler drains vmcnt before s_barrier -> all stores in L2
  if (threadIdx.x == 0) {
    unsigned old = __hip_atomic_fetch_add(leaf, 1u, __ATOMIC_ACQ_REL, __HIP_MEMORY_SCOPE_AGENT);
    if (old == ep * 8u - 1u) {
      __hip_atomic_fetch_add(root, 1u, __ATOMIC_ACQ_REL, __HIP_MEMORY_SCOPE_AGENT);
    }
    while (__hip_atomic_load(root, __ATOMIC_ACQUIRE, __HIP_MEMORY_SCOPE_AGENT) < ep * 8u) {
      __builtin_amdgcn_s_sleep(2);
    }
  }
  __syncthreads();
}

__global__ void __launch_bounds__(256) fgru_init(const float* __restrict__ h0,
    const float* __restrict__ gamma, const float* __restrict__ beta,
    short* __restrict__ z_g, float* __restrict__ stats, uint32_t* __restrict__ bar) {
  int idx = blockIdx.x * 256 + threadIdx.x;
  if (idx < NB * NU) {
    int c = idx & (NU - 1);
    float g = gamma[c];
    if (g == 0.0f) g = 1.0f;
    z_g[idx] = f2bf((h0[idx] - beta[c]) / g);
  }
  if (idx < NB * NWG) {
    // stats[row][jj][2]; idx = row*64+jj  -> fake stats so mu=0, rs=1 at t=0
    int jj = idx & 63;
    stats[idx * 2 + 0] = 0.0f;
    stats[idx * 2 + 1] = (jj == 0) ? (float)NU * (1.0f - 1e-3f) : 0.0f;
  }
  if (idx < 512) bar[idx] = 0u;  // root + leaves (first 2KB of ws)
}

__global__ void __launch_bounds__(256) fgru_main(
    const float* __restrict__ x, const float* __restrict__ Wg,
    const float* __restrict__ bg, const float* __restrict__ Wf,
    const float* __restrict__ bfv, const float* __restrict__ gamma,
    const float* __restrict__ beta, float* __restrict__ out,
    short* __restrict__ u_g, short* __restrict__ z_g,
    float* __restrict__ stats, uint32_t* __restrict__ bar) {
  __shared__ SMem sm;
  const int j = blockIdx.x;
  const int tid = threadIdx.x;
  const int l = tid & 63;
  const int w = tid >> 6;          // wave = m-tile index
  const int lk8 = (l >> 4) * 8;    // k offset within 32-chunk (A and B frags)
  const int ncol = l & 15;         // B-frag col / A-frag row
  const int swzn = (ncol & 7) << 3;
  const int mrow = w * 16 + (l & 15);

  // ---- startup: stage weights into LDS (bf16, transposed, XOR-swizzled) ----
  for (int i = tid; i < NU; i += 256) {
    sm.gamma_s[i] = gamma[i];
    sm.beta_s[i] = beta[i];
    sm.bfv_s[i] = bfv[i];
  }
  if (tid < GJ) sm.bg_s[tid] = bg[j * GJ + tid];
  __syncthreads();
  for (int i = tid; i < GJ * 512; i += 256) {
    int n = i >> 9, k = i & 511;
    int cg = j * GJ + n;
    int dst = n * 512 + (k ^ ((n & 7) << 3));
    sm.wgx[dst] = f2bf(Wg[(size_t)k * NC + cg]);
    sm.wgz[dst] = f2bf(sm.gamma_s[k] * Wg[(size_t)(512 + k) * NC + cg]);
  }
  for (int i = tid; i < ZJ * 1024; i += 256) {
    int n = i >> 10, k = i & 1023;
    int dst = n * 1024 + (k ^ ((n & 7) << 3));
    sm.wf[dst] = f2bf(Wf[(size_t)k * NU + j * ZJ + n]);
  }
  {
    int n = tid >> 4, part = tid & 15;
    float sb = 0.f, sg = 0.f;
    int cg = j * GJ + n;
    for (int k = part * 32; k < part * 32 + 32; ++k) {
      float wv = Wg[(size_t)(512 + k) * NC + cg];
      sb += sm.beta_s[k] * wv;
      sg += sm.gamma_s[k] * wv;
    }
    sm.red2[n][part][0] = sb;
    sm.red2[n][part][1] = sg;
  }
  __syncthreads();
  if (tid < GJ) {
    float sb = 0.f, sg = 0.f;
    #pragma unroll
    for (int p = 0; p < 16; ++p) { sb += sm.red2[tid][p][0]; sg += sm.red2[tid][p][1]; }
    sm.kb_s[tid] = sb;
    sm.kg_s[tid] = sg;
  }
  __syncthreads();

  uint32_t* root = bar;
  uint32_t* leaf = bar + 32 + (j >> 3) * 32;  // 8 groups of 8 WGs, 128B apart
  unsigned ep = 0;

  for (int t = 0; t <= NT; ++t) {
    // ---- LN stats from per-WG partials -> mu_s, rs_s ----
    {
      int row = tid >> 2, part = tid & 3;
      float s1 = 0.f, s2 = 0.f;
      const float* sp = &stats[row * 128 + part * 32];
      #pragma unroll
      for (int q2 = 0; q2 < 16; ++q2) { s1 += sp[q2 * 2]; s2 += sp[q2 * 2 + 1]; }
      sm.red[row][part][0] = s1;
      sm.red[row][part][1] = s2;
    }
    __syncthreads();
    if (tid < NB) {
      float s1 = 0.f, s2 = 0.f;
      #pragma unroll
      for (int p = 0; p < 4; ++p) { s1 += sm.red[tid][p][0]; s2 += sm.red[tid][p][1]; }
      float mu = s1 * (1.0f / NU);
      float var = s2 * (1.0f / NU) - mu * mu;
      sm.mu_s[tid] = mu;
      sm.rs_s[tid] = rsqrtf(var + 1e-3f);
    }
    __syncthreads();

    // ---- write out[:, t-1, jcols] = LN(z_prev) ----
    if (t > 0) {
      for (int e = tid; e < NB * ZJ; e += 256) {
        int row = e >> 3, c = e & 7;
        int col = j * ZJ + c;
        float zv = bf2f(z_g[row * NU + col]);
        float hv = (zv - sm.mu_s[row]) * sm.rs_s[row] * sm.gamma_s[col] + sm.beta_s[col];
        out[(size_t)row * NT * NU + (size_t)(t - 1) * NU + col] = hv;
      }
    }
    if (t == NT) break;

    // ---- phase A: gate cols [16j,16j+16) + u ----
    f32x4 accX = {0.f, 0.f, 0.f, 0.f};
    f32x4 accZ = {0.f, 0.f, 0.f, 0.f};
    const float* xrow = &x[(size_t)mrow * NT * ND + (size_t)t * ND];
    #pragma unroll 4
    for (int ks = 0; ks < 16; ++ks) {
      int k0 = ks * 32 + lk8;
      f32x4 xa = *(const f32x4*)(xrow + k0);
      f32x4 xb = *(const f32x4*)(xrow + k0 + 4);
      bf16x8 a;
      a[0] = f2bf(xa[0]); a[1] = f2bf(xa[1]); a[2] = f2bf(xa[2]); a[3] = f2bf(xa[3]);
      a[4] = f2bf(xb[0]); a[5] = f2bf(xb[1]); a[6] = f2bf(xb[2]); a[7] = f2bf(xb[3]);
      bf16x8 wx = *(const bf16x8*)&sm.wgx[ncol * 512 + (k0 ^ swzn)];
      accX = __builtin_amdgcn_mfma_f32_16x16x32_bf16(a, wx, accX, 0, 0, 0);
      bf16x8 az = *(const bf16x8*)&z_g[mrow * NU + k0];
      bf16x8 wz = *(const bf16x8*)&sm.wgz[ncol * 512 + (k0 ^ swzn)];
      accZ = __builtin_amdgcn_mfma_f32_16x16x32_bf16(az, wz, accZ, 0, 0, 0);
    }
    {
      int cg = j * GJ + ncol;
      float kbv = sm.kb_s[ncol], kgv = sm.kg_s[ncol], bgv = sm.bg_s[ncol];
      #pragma unroll
      for (int q = 0; q < 4; ++q) {
        int r = w * 16 + (l >> 4) * 4 + q;   // C/D: col=lane&15, row=(lane>>4)*4+q
        float mu = sm.mu_s[r], rs = sm.rs_s[r];
        float g = sigm(accX[q] + rs * accZ[q] + kbv - mu * rs * kgv + bgv);
        float comb;
        if (cg < ND) {
          comb = x[(size_t)r * NT * ND + (size_t)t * ND + cg];
        } else {
          int c = cg - ND;
          float zv = bf2f(z_g[r * NU + c]);
          comb = (zv - mu) * rs * sm.gamma_s[c] + sm.beta_s[c];
        }
        u_g[r * NC + cg] = f2bf(comb * g);
      }
    }

    ++ep;
    gbar(root, leaf, ep);   // publish u

    // ---- phase B: z cols [8j,8j+8) ----
    f32x4 acc = {0.f, 0.f, 0.f, 0.f};
    #pragma unroll 4
    for (int ks = 0; ks < 32; ++ks) {
      int k0 = ks * 32 + lk8;
      bf16x8 a = *(const bf16x8*)&u_g[mrow * NC + k0];
      bf16x8 b;
      if (ncol < ZJ) {
        b = *(const bf16x8*)&sm.wf[ncol * 1024 + (k0 ^ swzn)];
      } else {
        b[0]=0;b[1]=0;b[2]=0;b[3]=0;b[4]=0;b[5]=0;b[6]=0;b[7]=0;
      }
      acc = __builtin_amdgcn_mfma_f32_16x16x32_bf16(a, b, acc, 0, 0, 0);
    }
    #pragma unroll
    for (int q = 0; q < 4; ++q) {
      int r = w * 16 + (l >> 4) * 4 + q;
      float sv = 0.f, sq = 0.f;
      if (ncol < ZJ) {
        int col = j * ZJ + ncol;
        float zraw = acc[q] + sm.bfv_s[col];
        float s = zraw * sigm(zraw);   // silu
        z_g[r * NU + col] = f2bf(s);
        sv = s;
        sq = s * s;
      }
      sv += __shfl_xor(sv, 1); sq += __shfl_xor(sq, 1);
      sv += __shfl_xor(sv, 2); sq += __shfl_xor(sq, 2);
      sv += __shfl_xor(sv, 4); sq += __shfl_xor(sq, 4);
      if (ncol == 0) {
        stats[r * 128 + j * 2 + 0] = sv;
        stats[r * 128 + j * 2 + 1] = sq;
      }
    }

    ++ep;
    gbar(root, leaf, ep);   // publish z + stats
  }
}

extern "C" void kernel_launch(void* const* d_in, const int* in_sizes, int n_in,
                              void* d_out, int out_size, void* d_ws, size_t ws_size,
                              hipStream_t stream) {
  const float* x     = (const float*)d_in[0];
  const float* h0    = (const float*)d_in[1];
  const float* Wg    = (const float*)d_in[2];
  const float* bg    = (const float*)d_in[3];
  const float* Wf    = (const float*)d_in[4];
  const float* bfv   = (const float*)d_in[5];
  const float* gamma = (const float*)d_in[6];
  const float* beta  = (const float*)d_in[7];
  float* out = (float*)d_out;

  char* ws = (char*)d_ws;
  uint32_t* bar = (uint32_t*)ws;                       // 2KB: root + 8 leaves
  short* u_g    = (short*)(ws + 2048);                 // [64][1024] bf16 = 128KB
  short* z_g    = (short*)(ws + 2048 + NB * NC * 2);   // [64][512] bf16 = 64KB
  float* stats  = (float*)(ws + 2048 + NB * NC * 2 + NB * NU * 2);  // [64][64][2] f32

  fgru_init<<<128, 256, 0, stream>>>(h0, gamma, beta, z_g, stats, bar);
  fgru_main<<<NWG, 256, 0, stream>>>(x, Wg, bg, Wf, bfv, gamma, beta, out,
                                     u_g, z_g, stats, bar);
}

// Round 2
// 23439.627 us; speedup vs baseline: 1.1397x; 1.1397x over previous
//
#include <hip/hip_runtime.h>
#include <stdint.h>

#define NB 64
#define NT 1024
#define ND 512
#define NU 512
#define NC 1024
#define NWG 64
#define GJ 16   // gate cols per WG
#define ZJ 8    // z cols per WG

typedef __attribute__((ext_vector_type(8))) short bf16x8;
typedef __attribute__((ext_vector_type(4))) float f32x4;
typedef unsigned long long u64;

__device__ __forceinline__ short f2bf(float f) {
  union { float f; uint32_t u; } v; v.f = f;
  uint32_t r = (v.u + 0x7fffu + ((v.u >> 16) & 1u)) >> 16;
  return (short)(uint16_t)r;
}
__device__ __forceinline__ float bf2f(short s) {
  union { uint32_t u; float f; } v; v.u = ((uint32_t)(uint16_t)s) << 16;
  return v.f;
}
__device__ __forceinline__ float sigm(float x) { return 1.0f / (1.0f + __expf(-x)); }

// Coherent (IF-point) access helpers: relaxed agent-scope atomics -> sc1 L2-bypass.
__device__ __forceinline__ u64 ald8(const void* p) {
  return __hip_atomic_load((const u64*)p, __ATOMIC_RELAXED, __HIP_MEMORY_SCOPE_AGENT);
}
__device__ __forceinline__ void ast8(void* p, u64 v) {
  __hip_atomic_store((u64*)p, v, __ATOMIC_RELAXED, __HIP_MEMORY_SCOPE_AGENT);
}
__device__ __forceinline__ bf16x8 ald16(const short* p) {
  union { bf16x8 v; u64 q[2]; } u;
  u.q[0] = ald8(p);
  u.q[1] = ald8(p + 4);
  return u.v;
}
__device__ __forceinline__ unsigned ald4(const uint32_t* p) {
  return __hip_atomic_load(p, __ATOMIC_RELAXED, __HIP_MEMORY_SCOPE_AGENT);
}
__device__ __forceinline__ unsigned afadd(uint32_t* p) {
  return __hip_atomic_fetch_add(p, 1u, __ATOMIC_RELAXED, __HIP_MEMORY_SCOPE_AGENT);
}

struct SMem {
  // Weights as per-lane-linear MFMA B-fragments: [ks][lane 0..63][8 bf16].
  // lane l = (g<<4)|ncol holds B[k=ks*32+g*8+e][ncol], e=0..7 -> ds_read_b128 linear.
  short wgx[16 * 512];
  short wgz[16 * 512];
  short wf[32 * 512];    // ncol>=8 slots hold zeros (kills divergent branch)
  short u_s[NB * GJ];    // staging for u tile (8B-aligned: 64KB offset)
  float gamma_s[NU];
  float beta_s[NU];
  float bfv_s[NU];
  float bg_s[GJ];
  float kb_s[GJ];
  float kg_s[GJ];
  float mu_s[NB];
  float rs_s[NB];
  float z_s[NB * ZJ];    // f32 z tile (own cols), persists to next step's out-write
  float red[NB][4][2];
  float red2[GJ][16][2];
};

__global__ void __launch_bounds__(256) fgru_init(const float* __restrict__ h0,
    const float* __restrict__ gamma, const float* __restrict__ beta,
    short* __restrict__ z_g, float* __restrict__ stats, uint32_t* __restrict__ bar) {
  int idx = blockIdx.x * 256 + threadIdx.x;
  if (idx < NB * NU) {
    int c = idx & (NU - 1);
    float g = gamma[c];
    if (g == 0.0f) g = 1.0f;
    z_g[idx] = f2bf((h0[idx] - beta[c]) / g);
  }
  if (idx < NB * NWG) {
    int jj = idx & 63;   // fake stats so mu=0, rs=1 at t=0
    stats[idx * 2 + 0] = 0.0f;
    stats[idx * 2 + 1] = (jj == 0) ? (float)NU * (1.0f - 1e-3f) : 0.0f;
  }
  if (idx < 512) bar[idx] = 0u;
}

__global__ void __launch_bounds__(256, 1) fgru_main(
    const float* __restrict__ x, const float* __restrict__ Wg,
    const float* __restrict__ bg, const float* __restrict__ Wf,
    const float* __restrict__ bfv, const float* __restrict__ gamma,
    const float* __restrict__ beta, float* __restrict__ out,
    short* __restrict__ u_g, short* __restrict__ z_g,
    float* __restrict__ stats, uint32_t* __restrict__ bar) {
  __shared__ SMem sm;
  const int j = blockIdx.x;
  const int tid = threadIdx.x;
  const int l = tid & 63;
  const int w = tid >> 6;
  const int g4 = l >> 4;
  const int ncol = l & 15;
  const int lk8 = g4 * 8;
  const int mrow = w * 16 + ncol;
  const int cg = j * GJ + ncol;

  // ---- startup staging ----
  for (int i = tid; i < NU; i += 256) {
    sm.gamma_s[i] = gamma[i];
    sm.beta_s[i] = beta[i];
    sm.bfv_s[i] = bfv[i];
  }
  if (tid < GJ) sm.bg_s[tid] = bg[j * GJ + tid];
  __syncthreads();
  for (int i = tid; i < 16 * 512; i += 256) {
    int ks = i >> 9, slot = (i >> 3) & 63, e = i & 7;
    int gg = slot >> 4, n = slot & 15;
    int k = ks * 32 + gg * 8 + e;
    sm.wgx[i] = f2bf(Wg[(size_t)k * NC + j * GJ + n]);
    sm.wgz[i] = f2bf(sm.gamma_s[k] * Wg[(size_t)(512 + k) * NC + j * GJ + n]);
  }
  for (int i = tid; i < 32 * 512; i += 256) {
    int ks = i >> 9, slot = (i >> 3) & 63, e = i & 7;
    int gg = slot >> 4, n = slot & 15;
    int k = ks * 32 + gg * 8 + e;
    sm.wf[i] = (n < ZJ) ? f2bf(Wf[(size_t)k * NU + j * ZJ + n]) : (short)0;
  }
  {
    int n = tid >> 4, part = tid & 15;
    float sb = 0.f, sg = 0.f;
    int cgn = j * GJ + n;
    for (int k = part * 32; k < part * 32 + 32; ++k) {
      float wv = Wg[(size_t)(512 + k) * NC + cgn];
      sb += sm.beta_s[k] * wv;
      sg += sm.gamma_s[k] * wv;
    }
    sm.red2[n][part][0] = sb;
    sm.red2[n][part][1] = sg;
  }
  __syncthreads();
  if (tid < GJ) {
    float sb = 0.f, sg = 0.f;
    #pragma unroll
    for (int p = 0; p < 16; ++p) { sb += sm.red2[tid][p][0]; sg += sm.red2[tid][p][1]; }
    sm.kb_s[tid] = sb;
    sm.kg_s[tid] = sg;
  }

  uint32_t* root = bar;
  uint32_t* leaf = bar + 32 + (j >> 3) * 32;
  unsigned ep = 0;

  bf16x8 xa[16];
  float xcomb[4];
  auto PFX = [&](int tt) {
    const float* xr = x + (size_t)mrow * NT * ND + (size_t)tt * ND;
    #pragma unroll
    for (int ks = 0; ks < 16; ++ks) {
      f32x4 p0 = *(const f32x4*)(xr + ks * 32 + lk8);
      f32x4 p1 = *(const f32x4*)(xr + ks * 32 + lk8 + 4);
      bf16x8 a;
      a[0] = f2bf(p0[0]); a[1] = f2bf(p0[1]); a[2] = f2bf(p0[2]); a[3] = f2bf(p0[3]);
      a[4] = f2bf(p1[0]); a[5] = f2bf(p1[1]); a[6] = f2bf(p1[2]); a[7] = f2bf(p1[3]);
      xa[ks] = a;
    }
    if (cg < ND) {
      #pragma unroll
      for (int q = 0; q < 4; ++q)
        xcomb[q] = x[(size_t)(w * 16 + g4 * 4 + q) * NT * ND + (size_t)tt * ND + cg];
    }
  };
  PFX(0);
  __syncthreads();   // kb/kg ready

  for (int t = 0; t < NT; ++t) {
    // ---- phase A: batched coherent loads (all in flight) ----
    bf16x8 zr[16];
    #pragma unroll
    for (int ks = 0; ks < 16; ++ks)
      zr[ks] = ald16(z_g + mrow * NU + ks * 32 + lk8);
    u64 sreg[16];
    {
      const float* sp = stats + (tid >> 2) * 128 + (tid & 3) * 32;
      #pragma unroll
      for (int i2 = 0; i2 < 16; ++i2) sreg[i2] = ald8(sp + i2 * 2);
    }
    u64 zc[4];
    if (cg >= ND) {
      #pragma unroll
      for (int q = 0; q < 4; ++q)
        zc[q] = ald8(z_g + (w * 16 + g4 * 4 + q) * NU + ((cg - ND) & ~3));
    }

    // ---- MFMA: accX (prefetched x) + accZ ----
    f32x4 accX = {0.f, 0.f, 0.f, 0.f};
    f32x4 accZ = {0.f, 0.f, 0.f, 0.f};
    #pragma unroll
    for (int ks = 0; ks < 16; ++ks) {
      bf16x8 wx = *(const bf16x8*)&sm.wgx[ks * 512 + l * 8];
      bf16x8 wz = *(const bf16x8*)&sm.wgz[ks * 512 + l * 8];
      accX = __builtin_amdgcn_mfma_f32_16x16x32_bf16(xa[ks], wx, accX, 0, 0, 0);
      accZ = __builtin_amdgcn_mfma_f32_16x16x32_bf16(zr[ks], wz, accZ, 0, 0, 0);
    }

    // ---- LN stats reduce ----
    {
      union { u64 q; float f[2]; } uu;
      float s1 = 0.f, s2 = 0.f;
      #pragma unroll
      for (int i2 = 0; i2 < 16; ++i2) { uu.q = sreg[i2]; s1 += uu.f[0]; s2 += uu.f[1]; }
      sm.red[tid >> 2][tid & 3][0] = s1;
      sm.red[tid >> 2][tid & 3][1] = s2;
    }
    __syncthreads();
    if (tid < NB) {
      float s1 = 0.f, s2 = 0.f;
      #pragma unroll
      for (int p = 0; p < 4; ++p) { s1 += sm.red[tid][p][0]; s2 += sm.red[tid][p][1]; }
      float mu = s1 * (1.0f / NU);
      float var = s2 * (1.0f / NU) - mu * mu;
      sm.mu_s[tid] = mu;
      sm.rs_s[tid] = rsqrtf(var + 1e-3f);
    }
    __syncthreads();

    // ---- out[:, t-1, jcols] from f32 z_s ----
    if (t > 0) {
      #pragma unroll
      for (int e0 = 0; e0 < 2; ++e0) {
        int e = tid + e0 * 256;
        int row = e >> 3, c = e & 7, col = j * ZJ + c;
        out[(size_t)row * NT * NU + (size_t)(t - 1) * NU + col] =
            (sm.z_s[row * ZJ + c] - sm.mu_s[row]) * sm.rs_s[row] * sm.gamma_s[col] + sm.beta_s[col];
      }
    }

    // ---- gate epilogue -> u tile ----
    {
      float kbv = sm.kb_s[ncol], kgv = sm.kg_s[ncol], bgv = sm.bg_s[ncol];
      #pragma unroll
      for (int q = 0; q < 4; ++q) {
        int r = w * 16 + g4 * 4 + q;
        float mu = sm.mu_s[r], rs = sm.rs_s[r];
        float gt = sigm(accX[q] + rs * accZ[q] + kbv - mu * rs * kgv + bgv);
        float comb;
        if (cg < ND) {
          comb = xcomb[q];
        } else {
          union { u64 q2; short s4[4]; } uz;
          uz.q2 = zc[q];
          int c = cg - ND;
          float zv = bf2f(uz.s4[c & 3]);
          comb = (zv - mu) * rs * sm.gamma_s[c] + sm.beta_s[c];
        }
        sm.u_s[r * GJ + ncol] = f2bf(comb * gt);
      }
    }
    __syncthreads();
    ast8(u_g + (tid >> 2) * NC + j * GJ + (tid & 3) * 4, ((const u64*)sm.u_s)[tid]);

    // ---- barrier 1 (publish u); prefetch next x tile in the gap ----
    ++ep;
    __syncthreads();
    if (tid == 0) {
      unsigned old = afadd(leaf);
      if (old == ep * 8u - 1u) afadd(root);
    }
    if (t + 1 < NT) PFX(t + 1);
    if (tid == 0) {
      while (ald4(root) < ep * 8u) __builtin_amdgcn_s_sleep(1);
    }
    __syncthreads();

    // ---- phase B: z cols [8j,8j+8) ----
    bf16x8 ur[32];
    #pragma unroll
    for (int ks = 0; ks < 32; ++ks)
      ur[ks] = ald16(u_g + mrow * NC + ks * 32 + lk8);
    f32x4 a0 = {0.f, 0.f, 0.f, 0.f};
    f32x4 a1 = {0.f, 0.f, 0.f, 0.f};
    #pragma unroll
    for (int ks = 0; ks < 32; ks += 2) {
      bf16x8 b0 = *(const bf16x8*)&sm.wf[ks * 512 + l * 8];
      bf16x8 b1 = *(const bf16x8*)&sm.wf[(ks + 1) * 512 + l * 8];
      a0 = __builtin_amdgcn_mfma_f32_16x16x32_bf16(ur[ks], b0, a0, 0, 0, 0);
      a1 = __builtin_amdgcn_mfma_f32_16x16x32_bf16(ur[ks + 1], b1, a1, 0, 0, 0);
    }
    #pragma unroll
    for (int q = 0; q < 4; ++q) {
      int r = w * 16 + g4 * 4 + q;
      float sv = 0.f, sq = 0.f;
      if (ncol < ZJ) {
        float zraw = a0[q] + a1[q] + sm.bfv_s[j * ZJ + ncol];
        float s = zraw * sigm(zraw);
        sm.z_s[r * ZJ + ncol] = s;
        sv = s;
        sq = s * s;
      }
      sv += __shfl_xor(sv, 1); sq += __shfl_xor(sq, 1);
      sv += __shfl_xor(sv, 2); sq += __shfl_xor(sq, 2);
      sv += __shfl_xor(sv, 4); sq += __shfl_xor(sq, 4);
      if (ncol == 0) {
        union { u64 q2; float f[2]; } pv;
        pv.f[0] = sv; pv.f[1] = sq;
        ast8(stats + r * 128 + j * 2, pv.q2);
      }
    }
    __syncthreads();
    if (tid < 128) {
      int row = tid >> 1, b4 = (tid & 1) * 4;
      union { u64 q2; short s4[4]; } pz;
      #pragma unroll
      for (int i2 = 0; i2 < 4; ++i2) pz.s4[i2] = f2bf(sm.z_s[row * ZJ + b4 + i2]);
      ast8(z_g + row * NU + j * ZJ + b4, pz.q2);
    }

    // ---- barrier 2 (publish z + stats) ----
    ++ep;
    __syncthreads();
    if (tid == 0) {
      unsigned old = afadd(leaf);
      if (old == ep * 8u - 1u) afadd(root);
    }
    if (tid == 0) {
      while (ald4(root) < ep * 8u) __builtin_amdgcn_s_sleep(1);
    }
    __syncthreads();
  }

  // ---- final out-write for t = NT-1 ----
  {
    u64 sreg[16];
    const float* sp = stats + (tid >> 2) * 128 + (tid & 3) * 32;
    #pragma unroll
    for (int i2 = 0; i2 < 16; ++i2) sreg[i2] = ald8(sp + i2 * 2);
    union { u64 q; float f[2]; } uu;
    float s1 = 0.f, s2 = 0.f;
    #pragma unroll
    for (int i2 = 0; i2 < 16; ++i2) { uu.q = sreg[i2]; s1 += uu.f[0]; s2 += uu.f[1]; }
    sm.red[tid >> 2][tid & 3][0] = s1;
    sm.red[tid >> 2][tid & 3][1] = s2;
    __syncthreads();
    if (tid < NB) {
      float a = 0.f, b = 0.f;
      #pragma unroll
      for (int p = 0; p < 4; ++p) { a += sm.red[tid][p][0]; b += sm.red[tid][p][1]; }
      float mu = a * (1.0f / NU);
      float var = b * (1.0f / NU) - mu * mu;
      sm.mu_s[tid] = mu;
      sm.rs_s[tid] = rsqrtf(var + 1e-3f);
    }
    __syncthreads();
    #pragma unroll
    for (int e0 = 0; e0 < 2; ++e0) {
      int e = tid + e0 * 256;
      int row = e >> 3, c = e & 7, col = j * ZJ + c;
      out[(size_t)row * NT * NU + (size_t)(NT - 1) * NU + col] =
          (sm.z_s[row * ZJ + c] - sm.mu_s[row]) * sm.rs_s[row] * sm.gamma_s[col] + sm.beta_s[col];
    }
  }
}

extern "C" void kernel_launch(void* const* d_in, const int* in_sizes, int n_in,
                              void* d_out, int out_size, void* d_ws, size_t ws_size,
                              hipStream_t stream) {
  const float* x     = (const float*)d_in[0];
  const float* h0    = (const float*)d_in[1];
  const float* Wg    = (const float*)d_in[2];
  const float* bg    = (const float*)d_in[3];
  const float* Wf    = (const float*)d_in[4];
  const float* bfv   = (const float*)d_in[5];
  const float* gamma = (const float*)d_in[6];
  const float* beta  = (const float*)d_in[7];
  float* out = (float*)d_out;

  char* ws = (char*)d_ws;
  uint32_t* bar = (uint32_t*)ws;                       // 2KB: root + 8 leaves
  short* u_g    = (short*)(ws + 2048);                 // [64][1024] bf16
  short* z_g    = (short*)(ws + 2048 + NB * NC * 2);   // [64][512] bf16
  float* stats  = (float*)(ws + 2048 + NB * NC * 2 + NB * NU * 2);  // [64][64][2] f32

  fgru_init<<<128, 256, 0, stream>>>(h0, gamma, beta, z_g, stats, bar);
  fgru_main<<<NWG, 256, 0, stream>>>(x, Wg, bg, Wf, bfv, gamma, beta, out,
                                     u_g, z_g, stats, bar);
}